// Round 1
// baseline (967.848 us; speedup 1.0000x reference)
//
#include <hip/hip_runtime.h>

// Multi-scale ROIAlign (torchvision semantics, aligned=false, sampling_ratio=2).
// One thread per pooled pixel (m, py, px); precompute 16 (offset, weight) pairs
// in registers, then loop over all 256 channels: 16 gathers + 16 FMAs + 1 store.
// Coordinate math is amortized 256x. Writes are coalesced along pixel index.

#define C_CH 256

template <int P, int HW>
__global__ __launch_bounds__(256) void roi_align_kernel(
    const float* __restrict__ feat,   // [N, 256, HW, HW]
    const float* __restrict__ boxes,  // [M, 5]
    float* __restrict__ out,          // [M, 256, P, P]
    float scale, int M)
{
    constexpr int K = P * P;
    constexpr int HW2 = HW * HW;
    int t = blockIdx.x * blockDim.x + threadIdx.x;
    if (t >= M * K) return;

    int m   = t / K;
    int pix = t - m * K;
    int py  = pix / P;
    int px  = pix - py * P;

    const float* bx = boxes + m * 5;
    int   b  = (int)bx[0];
    float rx1 = bx[1] * scale;
    float ry1 = bx[2] * scale;
    float rx2 = bx[3] * scale;
    float ry2 = bx[4] * scale;
    float roi_w = fmaxf(rx2 - rx1, 1.0f);
    float roi_h = fmaxf(ry2 - ry1, 1.0f);
    float bin_w = roi_w * (1.0f / P);
    float bin_h = roi_h * (1.0f / P);

    int   off[16];
    float w[16];
    #pragma unroll
    for (int qy = 0; qy < 2; ++qy) {
        float ys = ry1 + ((float)py + (qy ? 0.75f : 0.25f)) * bin_h;
        bool vy = (ys >= -1.0f) && (ys <= (float)HW);
        float y = fminf(fmaxf(ys, 0.0f), (float)(HW - 1));
        int y0 = (int)y;                 // y >= 0, trunc == floor
        int y1i = min(y0 + 1, HW - 1);
        float ly = y - (float)y0;
        float hy = 1.0f - ly;
        #pragma unroll
        for (int qx = 0; qx < 2; ++qx) {
            float xs = rx1 + ((float)px + (qx ? 0.75f : 0.25f)) * bin_w;
            bool vx = (xs >= -1.0f) && (xs <= (float)HW);
            float x = fminf(fmaxf(xs, 0.0f), (float)(HW - 1));
            int x0 = (int)x;
            int x1i = min(x0 + 1, HW - 1);
            float lx = x - (float)x0;
            float hx = 1.0f - lx;
            float vw = (vy && vx) ? 0.25f : 0.0f;  // mean over 4 samples folded in
            int s = (qy * 2 + qx) * 4;
            off[s + 0] = y0  * HW + x0;   w[s + 0] = vw * hy * hx;
            off[s + 1] = y0  * HW + x1i;  w[s + 1] = vw * hy * lx;
            off[s + 2] = y1i * HW + x0;   w[s + 2] = vw * ly * hx;
            off[s + 3] = y1i * HW + x1i;  w[s + 3] = vw * ly * lx;
        }
    }

    const float* fb = feat + (size_t)b * C_CH * HW2;
    float* ob = out + (size_t)m * C_CH * K + pix;

    #pragma unroll 2
    for (int c = 0; c < C_CH; ++c) {
        const float* fc = fb + c * HW2;
        float acc = 0.0f;
        #pragma unroll
        for (int i = 0; i < 16; ++i) acc += w[i] * fc[off[i]];
        ob[c * K] = acc;
    }
}

extern "C" void kernel_launch(void* const* d_in, const int* in_sizes, int n_in,
                              void* d_out, int out_size, void* d_ws, size_t ws_size,
                              hipStream_t stream) {
    const float* x0 = (const float*)d_in[0];   // [2,256,128,128]
    const float* x1 = (const float*)d_in[1];   // [2,256,64,64]
    const float* x2 = (const float*)d_in[2];   // [2,256,32,32]
    const float* x3 = (const float*)d_in[3];   // [2,256,16,16]
    const float* boxes = (const float*)d_in[4];
    const int M = in_sizes[4] / 5;
    float* out = (float*)d_out;

    // Output level offsets (floats)
    const size_t o0 = 0;
    const size_t o1 = o0 + (size_t)M * C_CH * 4 * 4;
    const size_t o2 = o1 + (size_t)M * C_CH * 8 * 8;
    const size_t o3 = o2 + (size_t)M * C_CH * 16 * 16;

    const int BLOCK = 256;
    {
        int total = M * 4 * 4;
        roi_align_kernel<4, 128><<<(total + BLOCK - 1) / BLOCK, BLOCK, 0, stream>>>(
            x0, boxes, out + o0, 0.125f, M);
    }
    {
        int total = M * 8 * 8;
        roi_align_kernel<8, 64><<<(total + BLOCK - 1) / BLOCK, BLOCK, 0, stream>>>(
            x1, boxes, out + o1, 0.0625f, M);
    }
    {
        int total = M * 16 * 16;
        roi_align_kernel<16, 32><<<(total + BLOCK - 1) / BLOCK, BLOCK, 0, stream>>>(
            x2, boxes, out + o2, 0.03125f, M);
    }
    {
        int total = M * 32 * 32;
        roi_align_kernel<32, 16><<<(total + BLOCK - 1) / BLOCK, BLOCK, 0, stream>>>(
            x3, boxes, out + o3, 0.015625f, M);
    }
}

// Round 2
// 286.463 us; speedup vs baseline: 3.3786x; 3.3786x over previous
//
#include <hip/hip_runtime.h>

// Fused multi-scale ROIAlign (torchvision, aligned=false, sampling_ratio=2).
// One kernel over all 4 FPN levels. Work item = (level, channel-chunk, box, py, px);
// each thread computes 16 bilinear (offset,weight) pairs once, then loops over
// CC=32 channels: 16 gathers + 16 FMAs + 1 coalesced store per channel.
// Channel chunking (8 chunks) multiplies parallelism 8x so even the P=4 level
// fills the chip; fusing removes inter-level serialization (R1: the P=4 level
// alone ran 464us at 0.88% occupancy).

#define C_CH 256
#define CC 32                 // channels per thread
#define NCHUNK (C_CH / CC)

struct Params {
    const float* feat[4];
    const float* boxes;
    float scale[4];
    int hwShift[4];           // log2(HW)
    int pShift[4];            // log2(P)
    long long outBase[4];     // element offset into out
    int workBase[5];          // cumulative work items per level
    int M;
};

__global__ __launch_bounds__(256, 4) void msroi_kernel(Params p, float* __restrict__ out)
{
    int t = blockIdx.x * blockDim.x + threadIdx.x;
    if (t >= p.workBase[4]) return;

    int lvl = (t >= p.workBase[1]) + (t >= p.workBase[2]) + (t >= p.workBase[3]);
    int r = t - p.workBase[lvl];

    const int pSh  = p.pShift[lvl];
    const int hwSh = p.hwShift[lvl];
    const int HW   = 1 << hwSh;
    const int HW2  = HW * HW;
    const int K    = 1 << (2 * pSh);

    int pixN  = p.M << (2 * pSh);       // pixels per chunk-slice
    int chunk = r / pixN;               // one u32 div per thread, amortized CC x
    int pix   = r - chunk * pixN;
    int m     = pix >> (2 * pSh);
    int pib   = pix & (K - 1);
    int py    = pib >> pSh;
    int px    = pib & ((1 << pSh) - 1);

    const float* bxp = p.boxes + m * 5;
    int   b   = (int)bxp[0];
    float sc  = p.scale[lvl];
    float rx1 = bxp[1] * sc;
    float ry1 = bxp[2] * sc;
    float rx2 = bxp[3] * sc;
    float ry2 = bxp[4] * sc;
    float invP  = 1.0f / (float)(1 << pSh);
    float bin_w = fmaxf(rx2 - rx1, 1.0f) * invP;
    float bin_h = fmaxf(ry2 - ry1, 1.0f) * invP;

    int   off[16];
    float w[16];
    #pragma unroll
    for (int qy = 0; qy < 2; ++qy) {
        float ys = ry1 + ((float)py + (qy ? 0.75f : 0.25f)) * bin_h;
        bool vy = (ys >= -1.0f) && (ys <= (float)HW);
        float y = fminf(fmaxf(ys, 0.0f), (float)(HW - 1));
        int y0 = (int)y;                       // y >= 0 so trunc == floor
        int y1i = min(y0 + 1, HW - 1);
        float ly = y - (float)y0;
        float hy = 1.0f - ly;
        #pragma unroll
        for (int qx = 0; qx < 2; ++qx) {
            float xs = rx1 + ((float)px + (qx ? 0.75f : 0.25f)) * bin_w;
            bool vx = (xs >= -1.0f) && (xs <= (float)HW);
            float x = fminf(fmaxf(xs, 0.0f), (float)(HW - 1));
            int x0 = (int)x;
            int x1i = min(x0 + 1, HW - 1);
            float lx = x - (float)x0;
            float hx = 1.0f - lx;
            float vw = (vy && vx) ? 0.25f : 0.0f;   // mean over 2x2 samples folded in
            int s = (qy * 2 + qx) * 4;
            off[s + 0] = (y0  << hwSh) + x0;   w[s + 0] = vw * hy * hx;
            off[s + 1] = (y0  << hwSh) + x1i;  w[s + 1] = vw * hy * lx;
            off[s + 2] = (y1i << hwSh) + x0;   w[s + 2] = vw * ly * hx;
            off[s + 3] = (y1i << hwSh) + x1i;  w[s + 3] = vw * ly * lx;
        }
    }

    const float* fb = p.feat[lvl] + ((size_t)b * C_CH + chunk * CC) * (size_t)HW2;
    float* ob = out + p.outBase[lvl] + ((size_t)m * C_CH + chunk * CC) * (size_t)K + pib;

    #pragma unroll 2
    for (int c = 0; c < CC; ++c) {
        const float* fc = fb + c * HW2;
        float acc = 0.0f;
        #pragma unroll
        for (int i = 0; i < 16; ++i) acc += w[i] * fc[off[i]];
        ob[(size_t)c * K] = acc;
    }
}

extern "C" void kernel_launch(void* const* d_in, const int* in_sizes, int n_in,
                              void* d_out, int out_size, void* d_ws, size_t ws_size,
                              hipStream_t stream) {
    const int M = in_sizes[4] / 5;

    Params p;
    p.feat[0] = (const float*)d_in[0];  // [2,256,128,128]
    p.feat[1] = (const float*)d_in[1];  // [2,256,64,64]
    p.feat[2] = (const float*)d_in[2];  // [2,256,32,32]
    p.feat[3] = (const float*)d_in[3];  // [2,256,16,16]
    p.boxes   = (const float*)d_in[4];
    p.M = M;

    const float scales[4] = {0.125f, 0.0625f, 0.03125f, 0.015625f};
    const int hwSh[4] = {7, 6, 5, 4};   // 128,64,32,16
    const int pSh[4]  = {2, 3, 4, 5};   // 4,8,16,32

    long long ob = 0;
    int wb = 0;
    p.workBase[0] = 0;
    for (int l = 0; l < 4; ++l) {
        p.scale[l]   = scales[l];
        p.hwShift[l] = hwSh[l];
        p.pShift[l]  = pSh[l];
        p.outBase[l] = ob;
        int K = 1 << (2 * pSh[l]);
        ob += (long long)M * C_CH * K;
        wb += M * K * NCHUNK;
        p.workBase[l + 1] = wb;
    }

    int total = p.workBase[4];
    int blocks = (total + 255) / 256;
    msroi_kernel<<<blocks, 256, 0, stream>>>(p, (float*)d_out);
}